// Round 6
// baseline (1012.040 us; speedup 1.0000x reference)
//
#include <hip/hip_runtime.h>
#include <hip/hip_bf16.h>
#include <cstddef>

#define N_NODES 100000
#define N_EDGES 600000
#define DD 128
#define LL 3
#define CC 40
#define BN_EPS 1e-5f

// dtype-adaptive load/store: f32!=0 -> buffer holds float32, else bfloat16.
__device__ __forceinline__ float ldf(const void* p, long i, int f32) {
    return f32 ? ((const float*)p)[i] : __bfloat162float(((const __hip_bfloat16*)p)[i]);
}
__device__ __forceinline__ void stf(void* p, long i, float v, int f32) {
    if (f32) ((float*)p)[i] = v;
    else     ((__hip_bfloat16*)p)[i] = __float2bfloat16(v);
}

// ---------------- dtype detection (fp32 data read as bf16 -> garbage values) ----------------
__global__ __launch_bounds__(256) void k_detect(const void* __restrict__ x, int* __restrict__ dflag) {
    __shared__ int s[256];
    int t = threadIdx.x;
    const __hip_bfloat16* xb = (const __hip_bfloat16*)x;
    int bad = 0;
    for (int i = t; i < 4096; i += 256) {
        float v = __bfloat162float(xb[i]);
        float a = fabsf(v);
        if (!(a < 1e6f)) bad++;
        else if (v != 0.f && a < 1e-30f) bad++;
    }
    s[t] = bad; __syncthreads();
    for (int off = 128; off > 0; off >>= 1) {
        if (t < off) s[t] += s[t + off];
        __syncthreads();
    }
    if (t == 0) *dflag = (s[0] > 64) ? 1 : 0;
}

// ---------------- graph preprocessing ----------------

__global__ __launch_bounds__(256) void k_init(int* cnt, int* fpos, int* rowptr, float* stats) {
    int i = blockIdx.x * 256 + threadIdx.x;
    if (i < N_NODES) { cnt[i] = 0; fpos[i] = 0; }
    if (i < 6 * DD) stats[i] = 0.f;       // 3 layers x (sum[128], sumsq[128])
    if (i == 0) rowptr[N_NODES] = N_EDGES;
}

__global__ __launch_bounds__(256) void k_count(const int* __restrict__ ei, int* __restrict__ cnt) {
    int e = blockIdx.x * 256 + threadIdx.x;
    if (e < N_EDGES) atomicAdd(&cnt[ei[N_EDGES + e]], 1);  // dst row
}

__global__ __launch_bounds__(256) void k_scan1(const int* __restrict__ cnt, int* __restrict__ rowptr,
                                               int* __restrict__ bsum, float* __restrict__ dinv) {
    __shared__ int s[256];
    int t = threadIdx.x;
    int i = blockIdx.x * 256 + t;
    int v = (i < N_NODES) ? cnt[i] : 0;
    if (i < N_NODES) dinv[i] = 1.f / sqrtf((float)(1 + v));  // deg >= 1 (self-loop)
    s[t] = v; __syncthreads();
    for (int off = 1; off < 256; off <<= 1) {
        int x = (t >= off) ? s[t - off] : 0;
        __syncthreads();
        s[t] += x; __syncthreads();
    }
    if (i < N_NODES) rowptr[i] = s[t] - v;
    if (t == 255) bsum[blockIdx.x] = s[255];
}

__global__ __launch_bounds__(512) void k_scan2(int* bsum, int nb) {
    __shared__ int s[512];
    int t = threadIdx.x;
    int v = (t < nb) ? bsum[t] : 0;
    s[t] = v; __syncthreads();
    for (int off = 1; off < 512; off <<= 1) {
        int x = (t >= off) ? s[t - off] : 0;
        __syncthreads();
        s[t] += x; __syncthreads();
    }
    if (t < nb) bsum[t] = s[t] - v;
}

__global__ __launch_bounds__(256) void k_scan3(int* rowptr, const int* __restrict__ bsum) {
    int i = blockIdx.x * 256 + threadIdx.x;
    if (i < N_NODES) rowptr[i] += bsum[blockIdx.x];
}

__global__ __launch_bounds__(256) void k_fill(const int* __restrict__ ei, int* __restrict__ fpos,
                                              const int* __restrict__ rowptr, int* __restrict__ adj) {
    int e = blockIdx.x * 256 + threadIdx.x;
    if (e < N_EDGES) {
        int d = ei[N_EDGES + e];
        int p = atomicAdd(&fpos[d], 1);
        adj[rowptr[d] + p] = ei[e];
    }
}

// ---- row load + optional BN+PReLU. lane holds elements 2*lane, 2*lane+1 ----
__device__ __forceinline__ void load_act(const void* __restrict__ src, long row, int lane, int f,
                                         const float* __restrict__ bnp,
                                         float s0, float s1, float h0, float h1, float al,
                                         float& o0, float& o1) {
    if (bnp) {                      // fp32 pre-activation + BN + PReLU
        float2 v = ((const float2*)src)[row * 64 + lane];
        float y0 = fmaf(v.x, s0, h0), y1 = fmaf(v.y, s1, h1);
        o0 = (y0 > 0.f) ? y0 : al * y0;
        o1 = (y1 > 0.f) ? y1 : al * y1;
    } else if (f) {                 // raw fp32
        float2 v = ((const float2*)src)[row * 64 + lane];
        o0 = v.x; o1 = v.y;
    } else {                        // raw bf16 (2 elems per dword)
        unsigned u = ((const unsigned*)src)[row * 64 + lane];
        o0 = __uint_as_float(u << 16);
        o1 = __uint_as_float(u & 0xffff0000u);
    }
}

// ---- CSR aggregation (agg-first): out_i = dinv_i*(dinv_i*act_i + sum_j dinv_j*act_j) ----
// act = identity for layer 0 (src = x), else BN_{l-1}+PReLU applied inline on pre_{l-1}.
// 4 gathers in flight per iteration (latency x BW product needs ~4 outstanding rows/wave).

__global__ __launch_bounds__(256) void k_agg(const void* __restrict__ src,
                                             const int* __restrict__ rowptr,
                                             const int* __restrict__ adj,
                                             const float* __restrict__ dinv,
                                             const float* __restrict__ bnp,
                                             float* __restrict__ outp,
                                             const int* __restrict__ dflag) {
    int f = *dflag;
    int lane = threadIdx.x & 63;
    int i = blockIdx.x * 4 + (threadIdx.x >> 6);
    if (i >= N_NODES) return;
    float s0 = 0.f, s1 = 0.f, h0 = 0.f, h1 = 0.f, al = 0.f;
    if (bnp) {
        s0 = bnp[2 * lane];       s1 = bnp[2 * lane + 1];
        h0 = bnp[128 + 2 * lane]; h1 = bnp[129 + 2 * lane];
        al = bnp[256];
    }
    float di = dinv[i];
    int e0 = rowptr[i], e1 = rowptr[i + 1];
    float x0, x1;
    load_act(src, i, lane, f, bnp, s0, s1, h0, h1, al, x0, x1);
    float acc0 = di * x0, acc1 = di * x1;

    for (int base = e0; base < e1; base += 64) {
        int m = e1 - base; if (m > 64) m = 64;
        int aj = (lane < m) ? adj[base + lane] : 0;          // coalesced adjacency load
        float djl = (lane < m) ? dinv[aj] : 0.f;
        int t = 0;
        for (; t + 4 <= m; t += 4) {                          // 4 gathers in flight
            int jj[4]; float dd[4], px[4], py[4];
            #pragma unroll
            for (int u = 0; u < 4; ++u) {
                jj[u] = __shfl(aj, t + u);
                dd[u] = __shfl(djl, t + u);
            }
            #pragma unroll
            for (int u = 0; u < 4; ++u)
                load_act(src, jj[u], lane, f, bnp, s0, s1, h0, h1, al, px[u], py[u]);
            #pragma unroll
            for (int u = 0; u < 4; ++u) {
                acc0 += dd[u] * px[u];
                acc1 += dd[u] * py[u];
            }
        }
        for (; t < m; ++t) {
            int j0 = __shfl(aj, t);
            float d0 = __shfl(djl, t);
            float p0, p1;
            load_act(src, j0, lane, f, bnp, s0, s1, h0, h1, al, p0, p1);
            acc0 += d0 * p0;
            acc1 += d0 * p1;
        }
    }
    float2 r; r.x = di * acc0; r.y = di * acc1;
    ((float2*)outp)[(size_t)i * 64 + lane] = r;
}

// ---- fp32 GEMM: C[N x 128] = act(A)[N x 128] * W[128 x 128] + bias (opt relu) ----
// A streamed via L1/L2 broadcast, register double-buffered (8 loads in flight under
// the 128-FMA k4 body). W half-tile (64 cols) in LDS. 8x4 acc/thread.
// HASACT: apply BN+PReLU on A inline (head GEMM). stats: per-col sum/sumsq of C.

#define LOAD8(buf, kk4)                                                     \
    { _Pragma("unroll")                                                     \
      for (int i_ = 0; i_ < 8; ++i_) buf[i_] = A4[rbase + i_ * 32 + (kk4)]; }

#define ACT8(buf, kk4)                                                      \
    if (HASACT) {                                                           \
        float4 s4_ = ((const float4*)bnpA)[(kk4)];                          \
        float4 h4_ = ((const float4*)(bnpA + 128))[(kk4)];                  \
        _Pragma("unroll")                                                   \
        for (int i_ = 0; i_ < 8; ++i_) {                                    \
            float* av_ = (float*)&buf[i_];                                  \
            const float* sv_ = (const float*)&s4_;                          \
            const float* hv_ = (const float*)&h4_;                          \
            _Pragma("unroll")                                               \
            for (int k_ = 0; k_ < 4; ++k_) {                                \
                float y_ = fmaf(av_[k_], sv_[k_], hv_[k_]);                 \
                av_[k_] = (y_ > 0.f) ? y_ : alA * y_;                       \
            }                                                               \
        }                                                                   \
    }

#define FMA8(buf, kk4)                                                      \
    { _Pragma("unroll")                                                     \
      for (int kk_ = 0; kk_ < 4; ++kk_) {                                   \
          float4 wv_ = *(const float4*)&Wl[(kk4) * 4 + kk_][tx * 4];        \
          _Pragma("unroll")                                                 \
          for (int i_ = 0; i_ < 8; ++i_) {                                  \
              float av_ = ((const float*)&buf[i_])[kk_];                    \
              acc[i_][0] += av_ * wv_.x;                                    \
              acc[i_][1] += av_ * wv_.y;                                    \
              acc[i_][2] += av_ * wv_.z;                                    \
              acc[i_][3] += av_ * wv_.w;                                    \
          }                                                                 \
      } }

template <int HASACT>
__global__ __launch_bounds__(256, 4) void k_gemm2(const float* __restrict__ A,
                                                  const void* __restrict__ W, long woff,
                                                  const void* __restrict__ bias, long boff,
                                                  const float* __restrict__ bnpA,
                                                  float* __restrict__ stats,
                                                  float* __restrict__ Cout, int relu,
                                                  const int* __restrict__ dflag) {
    __shared__ float Wl[128][64];
    __shared__ float sred[16][64];
    int f = *dflag;
    int tid = threadIdx.x;
    int rowbase = (blockIdx.x >> 1) * 128;
    int colbase = (blockIdx.x & 1) * 64;

    if (f) {
        const float4* W4 = (const float4*)W + (woff >> 2);
        for (int u = tid; u < 128 * 16; u += 256) {
            int k = u >> 4, cq = u & 15;
            *(float4*)&Wl[k][cq * 4] = W4[k * 32 + (colbase >> 2) + cq];
        }
    } else {
        const unsigned* Wb = (const unsigned*)((const __hip_bfloat16*)W + woff);
        for (int u = tid; u < 128 * 32; u += 256) {
            int k = u >> 5, c2 = u & 31;
            unsigned v = Wb[k * 64 + (colbase >> 1) + c2];
            Wl[k][c2 * 2]     = __uint_as_float(v << 16);
            Wl[k][c2 * 2 + 1] = __uint_as_float(v & 0xffff0000u);
        }
    }
    __syncthreads();

    int tx = tid & 15;               // cols colbase + tx*4 .. +3
    int ty = tid >> 4;               // rows rowbase + ty*8 .. +7
    int r0 = rowbase + ty * 8;
    float acc[8][4];
    #pragma unroll
    for (int i = 0; i < 8; ++i)
        #pragma unroll
        for (int j = 0; j < 4; ++j) acc[i][j] = 0.f;

    const float4* A4 = (const float4*)A;
    float alA = HASACT ? bnpA[256] : 0.f;
    bool full = (rowbase + 128) <= N_NODES;

    if (full) {
        long rbase = (long)r0 * 32;
        float4 a0[8], a1[8];
        LOAD8(a0, 0); ACT8(a0, 0);
        #pragma unroll
        for (int k4 = 0; k4 < 32; k4 += 2) {
            if (k4 + 1 < 32) { LOAD8(a1, k4 + 1); }
            FMA8(a0, k4);
            if (k4 + 1 < 32) { ACT8(a1, k4 + 1); }
            if (k4 + 2 < 32) { LOAD8(a0, k4 + 2); }
            if (k4 + 1 < 32) { FMA8(a1, k4 + 1); }
            if (k4 + 2 < 32) { ACT8(a0, k4 + 2); }
        }
    } else {
        for (int k4 = 0; k4 < 32; ++k4) {
            float4 a[8];
            #pragma unroll
            for (int i = 0; i < 8; ++i) {
                float4 v = make_float4(0.f, 0.f, 0.f, 0.f);
                if (r0 + i < N_NODES) v = A4[(long)(r0 + i) * 32 + k4];
                a[i] = v;
            }
            ACT8(a, k4);
            FMA8(a, k4);
        }
    }

    float b4[4] = {0.f, 0.f, 0.f, 0.f};
    if (bias) {
        #pragma unroll
        for (int j = 0; j < 4; ++j) b4[j] = ldf(bias, boff + colbase + tx * 4 + j, f);
    }
    float ls[4] = {0.f, 0.f, 0.f, 0.f};
    float lq[4] = {0.f, 0.f, 0.f, 0.f};
    #pragma unroll
    for (int i = 0; i < 8; ++i) {
        int r = r0 + i;
        if (r < N_NODES) {
            float o[4];
            #pragma unroll
            for (int j = 0; j < 4; ++j) {
                float v = acc[i][j] + b4[j];
                if (relu) v = fmaxf(v, 0.f);
                o[j] = v;
                ls[j] += v;
                lq[j] += v * v;
            }
            *(float4*)&Cout[(long)r * 128 + colbase + tx * 4] = make_float4(o[0], o[1], o[2], o[3]);
        }
    }
    if (stats) {
        #pragma unroll
        for (int j = 0; j < 4; ++j) sred[ty][tx * 4 + j] = ls[j];
        __syncthreads();
        if (tid < 64) {
            float t = 0.f;
            #pragma unroll
            for (int g = 0; g < 16; ++g) t += sred[g][tid];
            atomicAdd(&stats[colbase + tid], t);
        }
        __syncthreads();
        #pragma unroll
        for (int j = 0; j < 4; ++j) sred[ty][tx * 4 + j] = lq[j];
        __syncthreads();
        if (tid < 64) {
            float t = 0.f;
            #pragma unroll
            for (int g = 0; g < 16; ++g) t += sred[g][tid];
            atomicAdd(&stats[128 + colbase + tid], t);
        }
    }
}

// scale[c]=gamma*rsqrt(var+eps); shift[c]=beta-mean*scale; [256]=prelu alpha
__global__ __launch_bounds__(128) void k_bnprep(const float* __restrict__ stats,
                                                const void* __restrict__ g, const void* __restrict__ b,
                                                const void* __restrict__ a, int l,
                                                float* __restrict__ bnp, const int* __restrict__ dflag) {
    int f = *dflag;
    int c = threadIdx.x;
    float mean = stats[c] / (float)N_NODES;
    float var = stats[128 + c] / (float)N_NODES - mean * mean;
    float inv = 1.f / sqrtf(var + BN_EPS);
    float s = ldf(g, (long)l * DD + c, f) * inv;
    bnp[c] = s;
    bnp[128 + c] = ldf(b, (long)l * DD + c, f) - mean * s;
    if (c == 0) bnp[256] = ldf(a, l, f);
}

// emb: BN_2+PReLU on pre_3 -> d_out (out dtype)
__global__ __launch_bounds__(256) void k_emb(const float* __restrict__ H, const float* __restrict__ bnp,
                                             void* __restrict__ out, const int* __restrict__ dflag) {
    int f = *dflag;
    long idx = (long)blockIdx.x * 256 + threadIdx.x;   // grid covers exactly N*DD
    int c = (int)(idx & 127);
    float al = bnp[256];
    float y = fmaf(H[idx], bnp[c], bnp[128 + c]);
    y = (y > 0.f) ? y : al * y;
    stf(out, idx, y, f);
}

// ---- head: logits = hidden @ Wh2 + bh2 ; argmax (first-max tie-break) ----

__global__ __launch_bounds__(256) void k_head(const float* __restrict__ Hd, const void* __restrict__ W2,
                                              const void* __restrict__ b2,
                                              void* __restrict__ out_base,
                                              const int* __restrict__ dflag) {
    __shared__ float Wl[128][40];
    __shared__ float bl[40];
    __shared__ float rv[32][8];
    __shared__ int ri[32][8];
    int f = *dflag;
    int tid = threadIdx.x;
    for (int u = tid; u < 128 * 40; u += 256) Wl[u / 40][u % 40] = ldf(W2, u, f);
    if (tid < 40) bl[tid] = ldf(b2, tid, f);
    __syncthreads();
    int rl = tid >> 3, g = tid & 7;
    long r = (long)blockIdx.x * 32 + rl;            // 3125*32 == N exactly
    float acc[5];
    #pragma unroll
    for (int j = 0; j < 5; ++j) acc[j] = bl[g * 5 + j];
    for (int k = 0; k < 128; ++k) {
        float h = Hd[r * 128 + k];
        #pragma unroll
        for (int j = 0; j < 5; ++j) acc[j] += h * Wl[k][g * 5 + j];
    }
    float best = acc[0]; int bi = 0;
    #pragma unroll
    for (int j = 1; j < 5; ++j)
        if (acc[j] > best) { best = acc[j]; bi = j; }   // strictly > keeps first max
    const long LOG_OFF = (long)N_NODES * DD;
    const long ARG_OFF = (long)N_NODES * (DD + CC);
    #pragma unroll
    for (int j = 0; j < 5; ++j) stf(out_base, LOG_OFF + r * 40 + g * 5 + j, acc[j], f);
    rv[rl][g] = best; ri[rl][g] = g * 5 + bi;
    __syncthreads();
    if (tid < 32) {
        long row = (long)blockIdx.x * 32 + tid;
        float bb = rv[tid][0]; int bbi = ri[tid][0];
        #pragma unroll
        for (int g2 = 1; g2 < 8; ++g2)
            if (rv[tid][g2] > bb) { bb = rv[tid][g2]; bbi = ri[tid][g2]; }
        stf(out_base, ARG_OFF + row, (float)bbi, f);
    }
}

// ---------------- launch ----------------

extern "C" void kernel_launch(void* const* d_in, const int* in_sizes, int n_in,
                              void* d_out, int out_size, void* d_ws, size_t ws_size,
                              hipStream_t stream) {
    const void* x   = d_in[0];
    const int* ei   = (const int*)d_in[1];
    const void* Ws  = d_in[2];
    const void* bs  = d_in[3];
    const void* gam = d_in[4];
    const void* bet = d_in[5];
    const void* pa  = d_in[6];
    const void* Wh1 = d_in[7];
    const void* bh1 = d_in[8];
    const void* Wh2 = d_in[9];
    const void* bh2 = d_in[10];

    char* w = (char*)d_ws;
    int* cnt     = (int*)w;    w += sizeof(int) * N_NODES;
    int* fpos    = (int*)w;    w += sizeof(int) * N_NODES;
    int* rowptr  = (int*)w;    w += sizeof(int) * (N_NODES + 4);
    int* adj     = (int*)w;    w += sizeof(int) * N_EDGES;
    int* bsum    = (int*)w;    w += sizeof(int) * 512;
    int* dflag   = (int*)w;    w += sizeof(int) * 4;
    float* dinv  = (float*)w;  w += sizeof(float) * N_NODES;
    float* stats = (float*)w;  w += sizeof(float) * (6 * DD);
    float* bnp   = (float*)w;  w += sizeof(float) * (3 * 512);
    float* bufA  = (float*)w;  w += sizeof(float) * (size_t)N_NODES * DD;
    float* bufB  = (float*)w;  w += sizeof(float) * (size_t)N_NODES * DD;

    const int scanBlocks = (N_NODES + 255) / 256;       // 391
    const int edgeBlocks = (N_EDGES + 255) / 256;       // 2344
    const int elemBlocks = (N_NODES * DD) / 256;        // 50000 exact
    const int gemmBlocks = ((N_NODES + 127) / 128) * 2; // 782 row-blocks x 2 col-halves
    const int aggBlocks  = (N_NODES + 3) / 4;           // 25000

    k_detect<<<1, 256, 0, stream>>>(x, dflag);
    k_init<<<scanBlocks, 256, 0, stream>>>(cnt, fpos, rowptr, stats);
    k_count<<<edgeBlocks, 256, 0, stream>>>(ei, cnt);
    k_scan1<<<scanBlocks, 256, 0, stream>>>(cnt, rowptr, bsum, dinv);
    k_scan2<<<1, 512, 0, stream>>>(bsum, scanBlocks);
    k_scan3<<<scanBlocks, 256, 0, stream>>>(rowptr, bsum);
    k_fill<<<edgeBlocks, 256, 0, stream>>>(ei, fpos, rowptr, adj);

    for (int l = 0; l < LL; ++l) {
        const void* src = (l == 0) ? x : (const void*)bufB;
        const float* bn = (l == 0) ? nullptr : (bnp + (l - 1) * 512);
        k_agg<<<aggBlocks, 256, 0, stream>>>(src, rowptr, adj, dinv, bn, bufA, dflag);
        k_gemm2<0><<<gemmBlocks, 256, 0, stream>>>(bufA, Ws, (long)l * DD * DD, bs, (long)l * DD,
                                                   nullptr, stats + l * 256, bufB, 0, dflag);
        k_bnprep<<<1, 128, 0, stream>>>(stats + l * 256, gam, bet, pa, l, bnp + l * 512, dflag);
    }

    k_emb<<<elemBlocks, 256, 0, stream>>>(bufB, bnp + 2 * 512, d_out, dflag);
    k_gemm2<1><<<gemmBlocks, 256, 0, stream>>>(bufB, Wh1, 0, bh1, 0, bnp + 2 * 512,
                                               nullptr, bufA, 1, dflag);
    k_head<<<(N_NODES / 32), 256, 0, stream>>>(bufA, Wh2, bh2, d_out, dflag);
}